// Round 7
// baseline (305.251 us; speedup 1.0000x reference)
//
#include <hip/hip_runtime.h>

// Problem constants
#define B_SZ 16
#define CIN  512
#define LIN  1024
#define LP   1022      // L - K + 1
#define HEADS 8
#define DH    64

typedef __attribute__((ext_vector_type(8))) short bf16x8;
typedef __attribute__((ext_vector_type(4))) float f32x4;

__device__ inline unsigned short f2bf(float f) {
    union { float f; unsigned int u; } c; c.f = f;
    unsigned int r = c.u + 0x7FFF + ((c.u >> 16) & 1);   // RNE
    return (unsigned short)(r >> 16);
}

// async global->LDS DMA, 16B per lane, LDS dst = wave-uniform base + lane*16
__device__ __forceinline__ void gl_lds16(const unsigned short* g, unsigned short* l) {
    __builtin_amdgcn_global_load_lds((const __attribute__((address_space(1))) void*)g,
                                     (__attribute__((address_space(3))) void*)l, 16, 0, 0);
}

// XOR swizzle on 16B granules: involution, preserves 8-granule blocks,
// spreads 16 consecutive rows across all 8 bank groups (2-way = free).
#define SWZ(G) ((G) ^ (((G) >> 3) & 7))

// ---------------------------------------------------------------------------
// xb cvt: x fp32 [b][512 i][1024 l] -> xb bf16 [b][1024 l][512 i]
// ---------------------------------------------------------------------------
__global__ __launch_bounds__(256) void xb_cvt_kernel(const float* __restrict__ x,
                                                     unsigned short* __restrict__ xb) {
    __shared__ float sm[64][68];
    const int t  = threadIdx.x;
    const int l0 = blockIdx.x * 64;
    const int i0 = blockIdx.y * 64;
    const int b  = blockIdx.z;
    const float* S = x + ((size_t)b * CIN + i0) * LIN;

    #pragma unroll
    for (int rr = 0; rr < 4; rr++) {
        int idx = rr * 1024 + t * 4;
        int ii = idx >> 6, lj = idx & 63;
        *(float4*)&sm[ii][lj] = *(const float4*)(S + (size_t)ii * LIN + l0 + lj);
    }
    __syncthreads();

    #pragma unroll
    for (int rr = 0; rr < 4; rr++) {
        int idx = rr * 1024 + t * 4;
        int l = idx >> 6, dj = idx & 63;
        ushort4 h;
        h.x = f2bf(sm[dj + 0][l]);
        h.y = f2bf(sm[dj + 1][l]);
        h.z = f2bf(sm[dj + 2][l]);
        h.w = f2bf(sm[dj + 3][l]);
        *(ushort4*)(xb + ((size_t)b * 1024 + l0 + l) * 512 + i0 + dj) = h;
    }
}

// ---------------------------------------------------------------------------
// wb cvt: w_c[o][i][kk] fp32 -> wb bf16 [kk][O=c*512+o][i]
// ---------------------------------------------------------------------------
__global__ __launch_bounds__(256) void wb_cvt_kernel(const float* __restrict__ w0,
                                                     const float* __restrict__ w1,
                                                     const float* __restrict__ w2,
                                                     unsigned short* __restrict__ wb) {
    const int kk = blockIdx.y;
    int flat = blockIdx.x * 256 + threadIdx.x;
    int i  = flat & 511;
    int oG = flat >> 9;
    int c  = oG >> 9, o = oG & 511;
    const float* w = (c == 0) ? w0 : (c == 1) ? w1 : w2;
    wb[(size_t)kk * 786432 + flat] = f2bf(w[o * 1536 + i * 3 + kk]);
}

// ---------------------------------------------------------------------------
// Fused 3-conv bf16 MFMA GEMM with global_load_lds staging + XOR-swizzled LDS.
// (unchanged — at the m97 structural plateau, ~822 TF)
// ---------------------------------------------------------------------------
__global__ __launch_bounds__(256) void conv_mfma_kernel(
        const unsigned short* __restrict__ xb,   // [16][1024][512]
        const unsigned short* __restrict__ wb,   // [3][1536][512]
        const float* __restrict__ b0, const float* __restrict__ b1,
        const float* __restrict__ b2,
        unsigned short* __restrict__ Qt, unsigned short* __restrict__ Kt,
        unsigned short* __restrict__ Vt, float qscale) {
    __shared__ unsigned short smem[16896];       // staging 16512 sh | vt 16896 sh
    unsigned short* xs = smem;                   // [132][32]
    unsigned short* ws = smem + 4224;            // [384][32]

    const int t    = threadIdx.x;
    const int wave = t >> 6;
    const int lane = t & 63;
    const int col  = lane & 15;
    const int quad = lane >> 4;
    const int wh   = wave >> 1;                  // o half
    const int wn   = wave & 1;                   // l half
    const int l0   = blockIdx.x * 128;
    const int o0   = blockIdx.y * 128;
    const int b    = blockIdx.z;

    f32x4 acc[4][4];
    #pragma unroll
    for (int i = 0; i < 4; i++)
        #pragma unroll
        for (int j = 0; j < 4; j++) acc[i][j] = (f32x4){0.f, 0.f, 0.f, 0.f};

    const unsigned short* xrow = xb + (size_t)b * 1024 * 512;

    for (int ic = 0; ic < 512; ic += 32) {
        __syncthreads();   // previous chunk's compute done before overwrite

        // ---- W DMA: 24 instrs (16 rows each), this wave does 6 ----
        #pragma unroll
        for (int j = 0; j < 6; j++) {
            int instr = wave * 6 + j;
            int Gg = SWZ(instr * 64 + lane);
            int p = Gg >> 2, q = Gg & 3;
            int kk = p >> 7, orow = p & 127;
            gl_lds16(wb + ((size_t)(kk * 1536 + o0 + orow)) * 512 + ic + q * 8,
                     ws + instr * 512);
        }
        // ---- X DMA: 8 instrs for rows 0..127, this wave does 2 ----
        #pragma unroll
        for (int j = 0; j < 2; j++) {
            int instr = wave * 2 + j;
            int Gg = SWZ(instr * 64 + lane);
            int p = Gg >> 2, q = Gg & 3;
            gl_lds16(xrow + (size_t)(l0 + p) * 512 + ic + q * 8,
                     xs + instr * 512);
        }
        // ---- halo rows 128,129 (checked, zero-fill OOB) ----
        if (t < 8) {
            int row = 128 + (t >> 2), sg = t & 3;
            int gl = l0 + row;
            bf16x8 v = (bf16x8){0, 0, 0, 0, 0, 0, 0, 0};
            if (gl < 1024) v = *(const bf16x8*)(xrow + (size_t)gl * 512 + ic + sg * 8);
            *(bf16x8*)&xs[SWZ(512 + t) * 8] = v;
        }
        __syncthreads();   // drains vmcnt (DMA) + lgkmcnt (halo)

        #pragma unroll
        for (int kk = 0; kk < 3; kk++) {
            bf16x8 af[4], bfr[4];
            #pragma unroll
            for (int ms = 0; ms < 4; ms++) {
                int G = ((kk * 128 + wh * 64 + ms * 16 + col) << 2) | quad;
                af[ms] = *(const bf16x8*)&ws[SWZ(G) * 8];
            }
            #pragma unroll
            for (int ns = 0; ns < 4; ns++) {
                int G = ((wn * 64 + ns * 16 + col + kk) << 2) | quad;
                bfr[ns] = *(const bf16x8*)&xs[SWZ(G) * 8];
            }
            #pragma unroll
            for (int ms = 0; ms < 4; ms++)
                #pragma unroll
                for (int ns = 0; ns < 4; ns++)
                    acc[ms][ns] = __builtin_amdgcn_mfma_f32_16x16x32_bf16(af[ms], bfr[ns], acc[ms][ns], 0, 0, 0);
        }
    }

    const int c = blockIdx.y >> 2;               // which conv (uniform per block)

    if (c < 2) {
        // ---- Q/K epilogue: direct bf16 stores to [bh][l][d] ----
        unsigned short* dst = (c == 0) ? Qt : Kt;
        const float* bias   = (c == 0) ? b0 : b1;
        const float sc      = (c == 0) ? qscale : 1.0f;
        const int h = (((o0 & 511) + wh * 64) >> 6) & 7;
        unsigned short* base = dst + (size_t)(b * 8 + h) * 65536;
        #pragma unroll
        for (int ms = 0; ms < 4; ms++) {
            int ob = (o0 & 511) + wh * 64 + ms * 16 + quad * 4;
            float bv[4];
            #pragma unroll
            for (int r = 0; r < 4; r++) bv[r] = bias[ob + r];
            int d0 = ms * 16 + quad * 4;
            #pragma unroll
            for (int ns = 0; ns < 4; ns++) {
                int l = l0 + wn * 64 + ns * 16 + col;
                ushort4 hv;
                hv.x = f2bf((acc[ms][ns][0] + bv[0]) * sc);
                hv.y = f2bf((acc[ms][ns][1] + bv[1]) * sc);
                hv.z = f2bf((acc[ms][ns][2] + bv[2]) * sc);
                hv.w = f2bf((acc[ms][ns][3] + bv[3]) * sc);
                *(ushort4*)(base + (size_t)l * 64 + d0) = hv;
            }
        }
    } else {
        // ---- V epilogue: LDS transpose then coalesced rows to [bh][d][1024] ----
        __syncthreads();
        unsigned short* vt = smem;               // [128][132]
        #pragma unroll
        for (int ms = 0; ms < 4; ms++) {
            int ob = (o0 & 511) + wh * 64 + ms * 16 + quad * 4;
            #pragma unroll
            for (int ns = 0; ns < 4; ns++) {
                int lc = wn * 64 + ns * 16 + col;
                #pragma unroll
                for (int r = 0; r < 4; r++)
                    vt[(wh * 64 + ms * 16 + quad * 4 + r) * 132 + lc] =
                        f2bf(acc[ms][ns][r] + b2[ob + r]);
            }
        }
        __syncthreads();
        #pragma unroll
        for (int it = 0; it < 8; it++) {
            int flat = it * 2048 + t * 8;
            int row = flat >> 7, colx = flat & 127;
            bf16x8 v = *(const bf16x8*)&vt[row * 132 + colx];
            int og = (o0 & 511) + row;
            int h = og >> 6, d = og & 63;
            *(bf16x8*)(Vt + ((size_t)(b * 8 + h) * 64 + d) * 1024 + l0 + colx) = v;
        }
    }
}

// ---------------------------------------------------------------------------
// Flash attention, bf16 MFMA, no-max softmax (p = 2^s, log2e folded into Q).
// BARRIER-FREE: K/V fragments loaded directly from global (L2-resident,
// operand-order layouts); only LDS use is the wave-private P transpose
// (lgkmcnt-ordered). No __syncthreads in the kernel at all -> waves stream
// independently and global loads pipeline across k-tiles.
// Block = (q-block of 128, bh); 4 waves x 32 q (2 groups of 16). 16 k-tiles.
// LDS: Ps only, 18KB.
// ---------------------------------------------------------------------------
__global__ __launch_bounds__(256, 4) void attn_kernel(
        const unsigned short* __restrict__ Qt,
        const unsigned short* __restrict__ Kt,
        const unsigned short* __restrict__ Vt,
        float* __restrict__ out) {
    __shared__ unsigned short Ps[4][32][72];     // [wave][q][k], wave-private

    const int t    = threadIdx.x;
    const int wave = t >> 6;
    const int lane = t & 63;
    const int col  = lane & 15;
    const int quad = lane >> 4;
    const int qb   = blockIdx.x;                 // 0..7
    const int bh   = blockIdx.y;                 // 0..127

    const size_t base64 = (size_t)bh * 1024 * 64;
    const int q0w = qb * 128 + wave * 32;

    // Q as B-operand frags: bq[g][h], rows q0w + g*16 + col
    bf16x8 bq[2][2];
    #pragma unroll
    for (int g = 0; g < 2; g++) {
        const unsigned short* qrow = Qt + base64 + (size_t)(q0w + g * 16 + col) * 64;
        bq[g][0] = *(const bf16x8*)(qrow + quad * 8);
        bq[g][1] = *(const bf16x8*)(qrow + 32 + quad * 8);
    }

    const bf16x8 ones = (bf16x8){0x3F80, 0x3F80, 0x3F80, 0x3F80,
                                 0x3F80, 0x3F80, 0x3F80, 0x3F80};

    f32x4 o[2][4];                               // [q-group][d-subtile]
    #pragma unroll
    for (int g = 0; g < 2; g++)
        #pragma unroll
        for (int d = 0; d < 4; d++) o[g][d] = (f32x4){0.f, 0.f, 0.f, 0.f};
    f32x4 osum[2];
    osum[0] = (f32x4){0.f, 0.f, 0.f, 0.f};
    osum[1] = (f32x4){0.f, 0.f, 0.f, 0.f};

    const unsigned short* kg0 = Kt + base64;
    const unsigned short* vg  = Vt + base64;
    unsigned short* Pw = &Ps[wave][0][0];

    for (int kt = 0; kt < 16; kt++) {
        const unsigned short* kg = kg0 + (size_t)kt * 4096;

        // ---- S^T = K Q^T : K A-frags straight from global ----
        #pragma unroll
        for (int sub = 0; sub < 4; sub++) {
            const unsigned short* krow = kg + (size_t)(sub * 16 + col) * 64;
            bf16x8 ak0 = *(const bf16x8*)(krow + quad * 8);
            bf16x8 ak1 = *(const bf16x8*)(krow + 32 + quad * 8);
            #pragma unroll
            for (int g = 0; g < 2; g++) {
                f32x4 a = (f32x4){0.f, 0.f, 0.f, 0.f};
                a = __builtin_amdgcn_mfma_f32_16x16x32_bf16(ak0, bq[g][0], a, 0, 0, 0);
                a = __builtin_amdgcn_mfma_f32_16x16x32_bf16(ak1, bq[g][1], a, 0, 0, 0);
                // p = 2^s (no max subtraction; |s| small); lane rows are
                // k = sub*16 + quad*4 + r
                unsigned int u[4];
                #pragma unroll
                for (int r = 0; r < 4; r++) {
                    union { float f; unsigned int u; } c;
                    c.f = exp2f(a[r]);
                    u[r] = c.u;
                }
                if (kt == 15 && sub == 3 && quad == 3) {  // mask keys 1022,1023
                    u[2] = 0; u[3] = 0;
                }
                uint2 pk;
                pk.x = (u[0] >> 16) | (u[1] & 0xFFFF0000u);
                pk.y = (u[2] >> 16) | (u[3] & 0xFFFF0000u);
                *(uint2*)&Pw[(g * 16 + col) * 72 + sub * 16 + quad * 4] = pk;
            }
        }

        // ---- P B-frags back from wave-private LDS (lgkmcnt only) ----
        bf16x8 bp[2][2];
        #pragma unroll
        for (int g = 0; g < 2; g++) {
            bp[g][0] = *(const bf16x8*)&Pw[(g * 16 + col) * 72 + quad * 8];
            bp[g][1] = *(const bf16x8*)&Pw[(g * 16 + col) * 72 + 32 + quad * 8];
        }

        // ---- O += V P : V A-frags straight from global ----
        #pragma unroll
        for (int dsub = 0; dsub < 4; dsub++) {
            const unsigned short* vrow = vg + (size_t)(dsub * 16 + col) * 1024 + kt * 64;
            bf16x8 av0 = *(const bf16x8*)(vrow + quad * 8);
            bf16x8 av1 = *(const bf16x8*)(vrow + 32 + quad * 8);
            #pragma unroll
            for (int g = 0; g < 2; g++) {
                o[g][dsub] = __builtin_amdgcn_mfma_f32_16x16x32_bf16(av0, bp[g][0], o[g][dsub], 0, 0, 0);
                o[g][dsub] = __builtin_amdgcn_mfma_f32_16x16x32_bf16(av1, bp[g][1], o[g][dsub], 0, 0, 0);
            }
        }
        #pragma unroll
        for (int g = 0; g < 2; g++) {
            osum[g] = __builtin_amdgcn_mfma_f32_16x16x32_bf16(ones, bp[g][0], osum[g], 0, 0, 0);
            osum[g] = __builtin_amdgcn_mfma_f32_16x16x32_bf16(ones, bp[g][1], osum[g], 0, 0, 0);
        }
    }

    // ---- epilogue: out[bh*64 + d][q] = o / rowsum ----
    // D layout: col = n = q (within group), rows m = d = dsub*16 + quad*4 + r
    #pragma unroll
    for (int g = 0; g < 2; g++) {
        int q = q0w + g * 16 + col;
        if (q < LP) {
            float inv = 1.0f / osum[g][0];       // all rows identical
            #pragma unroll
            for (int dsub = 0; dsub < 4; dsub++) {
                #pragma unroll
                for (int r = 0; r < 4; r++) {
                    int d = dsub * 16 + quad * 4 + r;
                    out[((size_t)bh * 64 + d) * LP + q] = o[g][dsub][r] * inv;
                }
            }
        }
    }
}

// ---------------------------------------------------------------------------
extern "C" void kernel_launch(void* const* d_in, const int* in_sizes, int n_in,
                              void* d_out, int out_size, void* d_ws, size_t ws_size,
                              hipStream_t stream) {
    const float* x  = (const float*)d_in[0];
    const float* w0 = (const float*)d_in[1];
    const float* b0 = (const float*)d_in[2];
    const float* w1 = (const float*)d_in[3];
    const float* b1 = (const float*)d_in[4];
    const float* w2 = (const float*)d_in[5];
    const float* b2 = (const float*)d_in[6];
    float* out = (float*)d_out;

    // workspace (ushort units): xb 8388608 | wb 2359296 | Qt/Kt/Vt 8388608 each
    unsigned short* xbp = (unsigned short*)d_ws;
    unsigned short* wbp = xbp + 8388608;
    unsigned short* Qt  = wbp + 2359296;
    unsigned short* Kt  = Qt + 8388608;
    unsigned short* Vt  = Kt + 8388608;

    // 1/sqrt(512) * log2(e): softmax computed as 2^s
    const float scale = 0.06375870864f;

    xb_cvt_kernel<<<dim3(16, 8, 16), 256, 0, stream>>>(x, xbp);
    wb_cvt_kernel<<<dim3(3072, 3), 256, 0, stream>>>(w0, w1, w2, wbp);
    conv_mfma_kernel<<<dim3(8, 12, 16), 256, 0, stream>>>(xbp, wbp, b0, b1, b2,
                                                          Qt, Kt, Vt, scale);
    attn_kernel<<<dim3(8, 128), 256, 0, stream>>>(Qt, Kt, Vt, out);
}